// Round 1
// baseline (151.373 us; speedup 1.0000x reference)
//
#include <hip/hip_runtime.h>

#define NUM_BINS 256
#define BATCH 32
#define CHW (3 * 512 * 512)   // 786432 elements per batch
#define N4 (CHW / 4)          // 196608 float4 per batch
#define BLOCKS_PER_BATCH 192  // 192*256 threads, 4 float4-iters each

// ---------------------------------------------------------------------------
// Kernel 1: per-batch 256-bin histogram of bin_idx = int((x*0.5+0.5)*255)
// Per-wave privatized LDS histograms (4 copies) -> global uint atomics.
// ---------------------------------------------------------------------------
__global__ __launch_bounds__(256) void hist_kernel(
    const float* __restrict__ img, unsigned int* __restrict__ hist) {
  __shared__ unsigned int lh[4][NUM_BINS];
  const int tid  = threadIdx.x;
  const int wave = tid >> 6;
  const int b    = blockIdx.y;

  // zero the 4 private histograms
  for (int i = tid; i < 4 * NUM_BINS; i += 256)
    ((unsigned int*)lh)[i] = 0u;
  __syncthreads();

  const float4* src = (const float4*)(img + (size_t)b * CHW);
  const int stride = BLOCKS_PER_BATCH * 256;
  for (int i = blockIdx.x * 256 + tid; i < N4; i += stride) {
    float4 v = src[i];
    int i0 = (int)((v.x * 0.5f + 0.5f) * 255.0f);
    int i1 = (int)((v.y * 0.5f + 0.5f) * 255.0f);
    int i2 = (int)((v.z * 0.5f + 0.5f) * 255.0f);
    int i3 = (int)((v.w * 0.5f + 0.5f) * 255.0f);
    i0 = min(max(i0, 0), NUM_BINS - 1);
    i1 = min(max(i1, 0), NUM_BINS - 1);
    i2 = min(max(i2, 0), NUM_BINS - 1);
    i3 = min(max(i3, 0), NUM_BINS - 1);
    atomicAdd(&lh[wave][i0], 1u);
    atomicAdd(&lh[wave][i1], 1u);
    atomicAdd(&lh[wave][i2], 1u);
    atomicAdd(&lh[wave][i3], 1u);
  }
  __syncthreads();

  // fold 4 copies, one global atomic per bin per block
  if (tid < NUM_BINS) {
    unsigned int s = lh[0][tid] + lh[1][tid] + lh[2][tid] + lh[3][tid];
    if (s) atomicAdd(&hist[b * NUM_BINS + tid], s);
  }
}

// ---------------------------------------------------------------------------
// Kernel 2: per-batch loss partial. 1 block per batch, 1 thread per bin.
// gen_cdf - tgt_cdf == inclusive_scan(p_gen - p_tgt)
// ---------------------------------------------------------------------------
__global__ __launch_bounds__(256) void loss_kernel(
    const unsigned int* __restrict__ hist, const float* __restrict__ tgt,
    float* __restrict__ partial) {
  __shared__ float s[NUM_BINS];
  const int b = blockIdx.x, tid = threadIdx.x;

  float g = (float)hist[b * NUM_BINS + tid];
  float t = tgt[b * NUM_BINS + tid];

  // block reduce: sum of g
  s[tid] = g; __syncthreads();
  for (int off = 128; off > 0; off >>= 1) {
    if (tid < off) s[tid] += s[tid + off];
    __syncthreads();
  }
  float sg = s[0]; __syncthreads();

  // block reduce: sum of t
  s[tid] = t; __syncthreads();
  for (int off = 128; off > 0; off >>= 1) {
    if (tid < off) s[tid] += s[tid + off];
    __syncthreads();
  }
  float st = s[0]; __syncthreads();

  float v = g / (sg + 1e-8f) - t / (st + 1e-8f);

  // inclusive Hillis-Steele scan over 256 bins
  s[tid] = v; __syncthreads();
  for (int off = 1; off < NUM_BINS; off <<= 1) {
    float a = (tid >= off) ? s[tid - off] : 0.0f;
    __syncthreads();
    v += a;
    s[tid] = v;
    __syncthreads();
  }

  // block reduce: sum |cdf diff|
  s[tid] = fabsf(v); __syncthreads();
  for (int off = 128; off > 0; off >>= 1) {
    if (tid < off) s[tid] += s[tid + off];
    __syncthreads();
  }
  if (tid == 0) partial[b] = s[0];
}

// ---------------------------------------------------------------------------
// Kernel 3: finalize — mean over 32*256 elements.
// ---------------------------------------------------------------------------
__global__ __launch_bounds__(64) void final_kernel(
    const float* __restrict__ partial, float* __restrict__ out) {
  const int tid = threadIdx.x;
  float v = (tid < BATCH) ? partial[tid] : 0.0f;
  for (int off = 32; off > 0; off >>= 1) v += __shfl_down(v, off);
  if (tid == 0) out[0] = v / (float)(BATCH * NUM_BINS);
}

extern "C" void kernel_launch(void* const* d_in, const int* in_sizes, int n_in,
                              void* d_out, int out_size, void* d_ws, size_t ws_size,
                              hipStream_t stream) {
  const float* img = (const float*)d_in[0];
  const float* tgt = (const float*)d_in[1];
  float* out = (float*)d_out;

  unsigned int* hist = (unsigned int*)d_ws;                      // 32*256 uint = 32 KB
  float* partial = (float*)((char*)d_ws + BATCH * NUM_BINS * 4); // 32 floats

  hipMemsetAsync(hist, 0, BATCH * NUM_BINS * sizeof(unsigned int), stream);

  dim3 hgrid(BLOCKS_PER_BATCH, BATCH, 1);
  hist_kernel<<<hgrid, 256, 0, stream>>>(img, hist);
  loss_kernel<<<BATCH, 256, 0, stream>>>(hist, tgt, partial);
  final_kernel<<<1, 64, 0, stream>>>(partial, out);
}

// Round 2
// 149.478 us; speedup vs baseline: 1.0127x; 1.0127x over previous
//
#include <hip/hip_runtime.h>

#define NUM_BINS 256
#define BATCH 32
#define CHW (3 * 512 * 512)     // 786432 elements per batch
#define N4 (CHW / 4)            // 196608 float4 per batch
#define BPB 64                  // hist blocks per batch -> 12 float4 iters/thread

// d_ws layout:
//   gh      : BATCH * BPB * NUM_BINS uint   (2 MB)  per-block partial hists
//   partial : BATCH floats
//   counter : 1 uint
#define GH_ELEMS (BATCH * BPB * NUM_BINS)

// ---------------------------------------------------------------------------
// Kernel 1: per-block partial histograms (plain stores, no init needed).
// Also zeroes the done-counter for kernel 2 (kernel-boundary coherence).
// ---------------------------------------------------------------------------
__global__ __launch_bounds__(256) void hist_kernel(
    const float* __restrict__ img, unsigned int* __restrict__ gh,
    unsigned int* __restrict__ counter) {
  __shared__ unsigned int lh[4][NUM_BINS];
  const int tid  = threadIdx.x;
  const int wave = tid >> 6;
  const int blk  = blockIdx.x;
  const int b    = blockIdx.y;

  if (blk == 0 && b == 0 && tid == 0) *counter = 0u;

  for (int i = tid; i < 4 * NUM_BINS; i += 256)
    ((unsigned int*)lh)[i] = 0u;
  __syncthreads();

  const float4* src = (const float4*)(img + (size_t)b * CHW);
  int i = blk * 256 + tid;
#pragma unroll 4
  for (int it = 0; it < N4 / (BPB * 256); ++it, i += BPB * 256) {
    float4 v = src[i];
    int i0 = (int)((v.x * 0.5f + 0.5f) * 255.0f);
    int i1 = (int)((v.y * 0.5f + 0.5f) * 255.0f);
    int i2 = (int)((v.z * 0.5f + 0.5f) * 255.0f);
    int i3 = (int)((v.w * 0.5f + 0.5f) * 255.0f);
    i0 = min(max(i0, 0), NUM_BINS - 1);
    i1 = min(max(i1, 0), NUM_BINS - 1);
    i2 = min(max(i2, 0), NUM_BINS - 1);
    i3 = min(max(i3, 0), NUM_BINS - 1);
    atomicAdd(&lh[wave][i0], 1u);
    atomicAdd(&lh[wave][i1], 1u);
    atomicAdd(&lh[wave][i2], 1u);
    atomicAdd(&lh[wave][i3], 1u);
  }
  __syncthreads();

  // fold 4 private copies -> one plain coalesced store per bin
  unsigned int s = lh[0][tid] + lh[1][tid] + lh[2][tid] + lh[3][tid];
  gh[((size_t)b * BPB + blk) * NUM_BINS + tid] = s;
}

// ---------------------------------------------------------------------------
// Kernel 2: per-batch loss + fused final reduction (last-block pattern).
// gen_cdf - tgt_cdf == inclusive_scan(p_gen - p_tgt)
// ---------------------------------------------------------------------------
__global__ __launch_bounds__(256) void loss_kernel(
    const unsigned int* __restrict__ gh, const float* __restrict__ tgt,
    float* __restrict__ partial, unsigned int* __restrict__ counter,
    float* __restrict__ out) {
  __shared__ float2 wsum[4];
  __shared__ float wtot[4];
  __shared__ float wabs[4];
  __shared__ int last_flag;
  const int b = blockIdx.x, tid = threadIdx.x;
  const int lane = tid & 63, wave = tid >> 6;

  // sum the 64 per-block partials for this bin
  float g = 0.0f;
  const unsigned int* gb = gh + (size_t)b * BPB * NUM_BINS + tid;
#pragma unroll 8
  for (int k = 0; k < BPB; ++k) g += (float)gb[k * NUM_BINS];
  float t = tgt[b * NUM_BINS + tid];

  // joint wave reduction of (g, t)
  float sg = g, st = t;
#pragma unroll
  for (int off = 32; off > 0; off >>= 1) {
    sg += __shfl_down(sg, off);
    st += __shfl_down(st, off);
  }
  if (lane == 0) wsum[wave] = make_float2(sg, st);
  __syncthreads();
  float sgT = wsum[0].x + wsum[1].x + wsum[2].x + wsum[3].x;
  float stT = wsum[0].y + wsum[1].y + wsum[2].y + wsum[3].y;

  float v = g / (sgT + 1e-8f) - t / (stT + 1e-8f);

  // inclusive scan: shfl within wave, LDS wave offsets
  float sv = v;
#pragma unroll
  for (int off = 1; off < 64; off <<= 1) {
    float n = __shfl_up(sv, off);
    if (lane >= off) sv += n;
  }
  if (lane == 63) wtot[wave] = sv;
  __syncthreads();
  float prefix = 0.0f;
  for (int w = 0; w < wave; ++w) prefix += wtot[w];
  sv += prefix;

  // reduce sum |cdf diff|
  float a = fabsf(sv);
#pragma unroll
  for (int off = 32; off > 0; off >>= 1) a += __shfl_down(a, off);
  if (lane == 0) wabs[wave] = a;
  __syncthreads();

  if (tid == 0) {
    float tot = wabs[0] + wabs[1] + wabs[2] + wabs[3];
    atomicExch(&partial[b], tot);       // device-scope publish
    __threadfence();
    unsigned int old = atomicAdd(counter, 1u);
    last_flag = (old == BATCH - 1) ? 1 : 0;
  }
  __syncthreads();

  // last block: reduce the 32 partials to the scalar mean
  if (last_flag && wave == 0) {
    float pv = (lane < BATCH) ? atomicAdd(&partial[lane], 0.0f) : 0.0f;
#pragma unroll
    for (int off = 32; off > 0; off >>= 1) pv += __shfl_down(pv, off);
    if (lane == 0) out[0] = pv / (float)(BATCH * NUM_BINS);
  }
}

extern "C" void kernel_launch(void* const* d_in, const int* in_sizes, int n_in,
                              void* d_out, int out_size, void* d_ws, size_t ws_size,
                              hipStream_t stream) {
  const float* img = (const float*)d_in[0];
  const float* tgt = (const float*)d_in[1];
  float* out = (float*)d_out;

  unsigned int* gh = (unsigned int*)d_ws;
  float* partial = (float*)((char*)d_ws + GH_ELEMS * sizeof(unsigned int));
  unsigned int* counter = (unsigned int*)(partial + BATCH);

  dim3 hgrid(BPB, BATCH, 1);
  hist_kernel<<<hgrid, 256, 0, stream>>>(img, gh, counter);
  loss_kernel<<<BATCH, 256, 0, stream>>>(gh, tgt, partial, counter, out);
}